// Round 13
// baseline (180.718 us; speedup 1.0000x reference)
//
#include <hip/hip_runtime.h>

#define B_  8
#define S_  1024
#define E_  512
#define LOG2E 1.44269504088896340736f

typedef _Float16 half_t;
typedef _Float16 half2_t __attribute__((ext_vector_type(2)));
typedef _Float16 half8_t __attribute__((ext_vector_type(8)));
typedef float    floatx16 __attribute__((ext_vector_type(16)));
typedef unsigned int uint2v __attribute__((ext_vector_type(2)));
typedef unsigned int uint4v __attribute__((ext_vector_type(4)));

#define PHI_BYTES ((size_t)64 * S_ * 32 * 2)       // 4 MB per phi table
#define VT_BYTES  ((size_t)64 * 16 * 4096 * 2)     // 8 MB (tiled)

#define GLOAD_LDS16(g, l)                                                        \
    __builtin_amdgcn_global_load_lds((const __attribute__((address_space(1))) void*)(g), \
                                     (__attribute__((address_space(3))) void*)(l), 16, 0, 0)

// ---------------------------------------------------------------------------
// Precompute (byte-identical to the passing r12 version).
// ---------------------------------------------------------------------------
__global__ __launch_bounds__(256, 4) void precompute_kernel(const float* __restrict__ x,
                                                            half_t* __restrict__ phiA,
                                                            half_t* __restrict__ phiB,
                                                            half_t* __restrict__ vt) {
    const int orig = blockIdx.x;
    const int xcd  = orig & 7, slot = orig >> 3;
    const int bh   = xcd * 8 + (slot & 7);
    const int chunk = slot >> 3;
    const int b  = bh >> 3, h = bh & 7;
    const int j0 = chunk * 64;
    const int t  = threadIdx.x;
    __shared__ __align__(16) float vf[64][76];

    const float* xb = x + (size_t)b * S_ * E_ + h * 64;

    {
        const int j = t >> 2, dq = (t & 3) * 4;
        const float* row = xb + (size_t)(j0 + j) * E_;
        #pragma unroll
        for (int q = 0; q < 4; ++q)
            *(float4*)&vf[j][dq + q * 16] = *(const float4*)(row + dq + q * 16);
    }
    __syncthreads();

    if (t < 128) {
        const int jj = t >> 1, sel = t & 1;
        float4 xw = *(const float4*)&vf[jj][sel * 4];
        float xi[4] = {xw.x, xw.y, xw.z, xw.w};
        float c[4], s[4];
        #pragma unroll
        for (int q = 0; q < 4; ++q) {
            float v = xi[q] * 0.5f;
            c[q] = __cosf(v); s[q] = __sinf(v);
        }
        float pa[4] = {c[0]*c[1], s[0]*c[1], c[0]*s[1], s[0]*s[1]};
        float pb[4] = {c[2]*c[3], s[2]*c[3], c[2]*s[3], s[2]*s[3]};
        const float scale = sel ? LOG2E : 1.0f;
        half_t hB[16], hA[16];
        #pragma unroll
        for (int f = 0; f < 16; ++f) {
            float v = pa[f & 3] * pb[f >> 2];
            hB[f] = (half_t)v;
            hA[f] = (half_t)(v * scale);
        }
        size_t off = ((size_t)bh * S_ + j0 + jj) * 32 + (sel ? 0 : 16);
        *(half8_t*)(phiB + off)     = *(half8_t*)&hB[0];
        *(half8_t*)(phiB + off + 8) = *(half8_t*)&hB[8];
        *(half8_t*)(phiA + off)     = *(half8_t*)&hA[0];
        *(half8_t*)(phiA + off + 8) = *(half8_t*)&hA[8];
    }

    {
        const int d = t >> 2, jg = (t & 3) * 16;
        half_t hv[16];
        #pragma unroll
        for (int k = 0; k < 16; ++k) hv[k] = (half_t)vf[jg + k][d];
        const int slot0 = (t & 3) * 2;
        half_t* base = vt + ((size_t)bh * 16 + chunk) * 4096;
        *(half8_t*)(base + (slot0 + 0) * 512 + d * 8) = *(half8_t*)&hv[0];
        *(half8_t*)(base + (slot0 + 1) * 512 + d * 8) = *(half8_t*)&hv[8];
    }
}

// ---------------------------------------------------------------------------
// Main kernel = passing r12 pipeline, with the ENTIRE sweep wrapped in
// rep in {0,1} — ATTRIBUTION INSTRUMENTATION. Before rep 1, all accumulators
// are multiplied by an opaque zero (inline-asm v_mov_b32 0: not foldable, so
// rep 0 isn't DCE'd; x*0.f == 0.f exactly) and the sweep re-runs, producing
// bit-identical output at ~2x duration. Purpose: (a) total-95.6 = attn's
// true single-sweep cost; (b) pushes attn above the ~45 us fill cutoff into
// the rocprof top-5 -> first-ever counters for this kernel.
// rep-boundary WAR on buf0 is safe (last readers passed 2 barriers earlier).
// ---------------------------------------------------------------------------
__global__ __launch_bounds__(256, 2) void attn_kernel(const half_t* __restrict__ phiA,
                                                      const half_t* __restrict__ phiB,
                                                      const half_t* __restrict__ vt,
                                                      float* __restrict__ out) {
    const int orig = blockIdx.x;
    const int xcd  = orig & 7, slot = orig >> 3;
    const int bh   = xcd * 8 + (slot & 7);      // 8 bh per XCD
    const int iblk = slot >> 3;                  // 16 i-blocks
    const int b    = bh >> 3, h = bh & 7;
    const int i0   = iblk * 64;
    const int t    = threadIdx.x;
    const int wv   = t >> 6, ln = t & 63;
    const int m    = ln & 31, hf = ln >> 5;
    const int ib   = wv >> 1, jb = wv & 1;

    __shared__ __align__(16) unsigned char smem_u[65536];
    half_t (&sh_v)[2][16384]    = *reinterpret_cast<half_t(*)[2][16384]>(smem_u);
    float  (&sh_red)[2][32][64] = *reinterpret_cast<float(*)[2][32][64]>(smem_u);
    float  (&sh_den)[2][64]     = *reinterpret_cast<float(*)[2][64]>(smem_u + 16384 * 4);

    const half_t* phbA = phiA + (size_t)bh * S_ * 32;
    const half_t* phbB = phiB + (size_t)bh * S_ * 32;
    const half_t* vtb  = vt + (size_t)bh * 65536;

    half8_t biH, biL;
    {
        const half_t* pr = phbB + (size_t)(i0 + ib * 32 + m) * 32 + hf * 8;
        biH = *(const half8_t*)pr;
        biL = *(const half8_t*)(pr + 16);
    }

    floatx16 acc0, acc1, z;
    #pragma unroll
    for (int k = 0; k < 16; ++k) { acc0[k] = 0.f; acc1[k] = 0.f; z[k] = 0.f; }
    float d0 = 0.f, d1 = 0.f;

    const int s0 = 8 * wv;   // wave's 8 staging slots (of 32 per period)

    // opaque zero: compiler cannot fold, keeps rep 0's work live (rule #17)
    float zk;
    asm volatile("v_mov_b32 %0, 0" : "=v"(zk));

    for (int rep = 0; rep < 2; ++rep) {
        if (rep) {
            #pragma unroll
            for (int k = 0; k < 16; ++k) { acc0[k] *= zk; acc1[k] *= zk; }
            d0 *= zk; d1 *= zk;
        }

        // prologue: stage period 0 into buf0, prefetch all 4 aj pairs
        #pragma unroll
        for (int i = 0; i < 8; ++i)
            GLOAD_LDS16(vtb + (s0 + i) * 512 + ln * 8, &sh_v[0][(s0 + i) * 512]);
        __builtin_amdgcn_sched_barrier(0);
        half8_t aH[4], aL[4];
        #pragma unroll
        for (int qi = 0; qi < 4; ++qi) {
            const half_t* ar = phbA + (size_t)((jb + 2 * qi) * 32 + m) * 32 + hf * 8;
            aH[qi] = *(const half8_t*)ar;
            aL[qi] = *(const half8_t*)(ar + 16);
        }
        asm volatile("s_waitcnt vmcnt(8)" ::: "memory");   // stages landed
        __builtin_amdgcn_s_barrier();

        #pragma unroll
        for (int tt = 0; tt < 4; ++tt) {        // 4 periods x 256 j
            const int cur = tt & 1;
            const int np  = (tt + 1) & 3;        // wrapped prefetch

            if (tt < 3) {
                const half_t* vs = vtb + (size_t)(tt + 1) * 16384;
                #pragma unroll
                for (int i = 0; i < 8; ++i)
                    GLOAD_LDS16(vs + (s0 + i) * 512 + ln * 8, &sh_v[cur ^ 1][(s0 + i) * 512]);
            }
            __builtin_amdgcn_sched_barrier(0);   // pin: stages before aj loads

            half8_t nH[4], nL[4];
            #pragma unroll
            for (int qi = 0; qi < 4; ++qi) {
                const half_t* ar = phbA + (size_t)(np * 256 + (jb + 2 * qi) * 32 + m) * 32 + hf * 8;
                nH[qi] = *(const half8_t*)ar;
                nL[qi] = *(const half8_t*)(ar + 16);
            }

            #pragma unroll
            for (int qi = 0; qi < 4; ++qi) {
                const int q = jb + 2 * qi;
                const half_t* vb = sh_v[cur];
                half8_t b00 = *(const half8_t*)&vb[(q * 4 + 0 + hf) * 512 + m * 8];
                half8_t b01 = *(const half8_t*)&vb[(q * 4 + 2 + hf) * 512 + m * 8];
                half8_t b10 = *(const half8_t*)&vb[(q * 4 + 0 + hf) * 512 + (32 + m) * 8];
                half8_t b11 = *(const half8_t*)&vb[(q * 4 + 2 + hf) * 512 + (32 + m) * 8];

                floatx16 sH = __builtin_amdgcn_mfma_f32_32x32x16_f16(aH[qi], biH, z, 0, 0, 0);
                floatx16 sL = __builtin_amdgcn_mfma_f32_32x32x16_f16(aL[qi], biL, z, 0, 0, 0);

                unsigned int dwa[4], dwb[4];
                #pragma unroll
                for (int g = 0; g < 4; ++g) {
                    float p[4];
                    #pragma unroll
                    for (int r = 0; r < 4; ++r) {
                        float sc = sH[4 * g + r] * sL[4 * g + r];
                        p[r] = __builtin_amdgcn_exp2f(__builtin_fabsf(sc));
                    }
                    d0 += p[0] + p[2];
                    d1 += p[1] + p[3];
                    half2_t ha = {(half_t)p[0], (half_t)p[1]};
                    half2_t hb = {(half_t)p[2], (half_t)p[3]};
                    dwa[g] = __builtin_bit_cast(unsigned int, ha);
                    dwb[g] = __builtin_bit_cast(unsigned int, hb);
                }
                uint2v swA0 = __builtin_amdgcn_permlane32_swap(dwa[0], dwa[1], false, false);
                uint2v swB0 = __builtin_amdgcn_permlane32_swap(dwb[0], dwb[1], false, false);
                uint2v swA1 = __builtin_amdgcn_permlane32_swap(dwa[2], dwa[3], false, false);
                uint2v swB1 = __builtin_amdgcn_permlane32_swap(dwb[2], dwb[3], false, false);
                half8_t ap0 = __builtin_bit_cast(half8_t, (uint4v){swA0.x, swB0.x, swA0.y, swB0.y});
                half8_t ap1 = __builtin_bit_cast(half8_t, (uint4v){swA1.x, swB1.x, swA1.y, swB1.y});

                acc0 = __builtin_amdgcn_mfma_f32_32x32x16_f16(ap0, b00, acc0, 0, 0, 0);
                acc0 = __builtin_amdgcn_mfma_f32_32x32x16_f16(ap1, b01, acc0, 0, 0, 0);
                acc1 = __builtin_amdgcn_mfma_f32_32x32x16_f16(ap0, b10, acc1, 0, 0, 0);
                acc1 = __builtin_amdgcn_mfma_f32_32x32x16_f16(ap1, b11, acc1, 0, 0, 0);
            }

            if (tt < 3) { asm volatile("s_waitcnt vmcnt(8)" ::: "memory"); }
            __builtin_amdgcn_s_barrier();
            #pragma unroll
            for (int qi = 0; qi < 4; ++qi) { aH[qi] = nH[qi]; aL[qi] = nL[qi]; }
        }
    }

    // full drain before reusing sh_v's storage as sh_red/sh_den
    __syncthreads();

    // ---- epilogue: combine hf halves of denominator, then jb partials of O
    float dtot = d0 + d1;
    dtot += __shfl_xor(dtot, 32, 64);
    sh_den[jb][ib * 32 + m] = dtot;
    if (jb == 1) {
        #pragma unroll
        for (int reg = 0; reg < 16; ++reg) {
            int il = (reg & 3) + 8 * (reg >> 2) + 4 * hf;
            sh_red[ib][il][m]      = acc0[reg];
            sh_red[ib][il][32 + m] = acc1[reg];
        }
    }
    __syncthreads();
    if (jb == 0) {
        #pragma unroll
        for (int reg = 0; reg < 16; ++reg) {
            int il = (reg & 3) + 8 * (reg >> 2) + 4 * hf;
            float inv = 1.f / (sh_den[0][ib * 32 + il] + sh_den[1][ib * 32 + il]);
            size_t base = ((size_t)(b * S_ + i0 + ib * 32 + il)) * E_ + h * 64 + m;
            __builtin_nontemporal_store((acc0[reg] + sh_red[ib][il][m])      * inv, &out[base]);
            __builtin_nontemporal_store((acc1[reg] + sh_red[ib][il][32 + m]) * inv, &out[base + 32]);
        }
    }
}

extern "C" void kernel_launch(void* const* d_in, const int* in_sizes, int n_in,
                              void* d_out, int out_size, void* d_ws, size_t ws_size,
                              hipStream_t stream) {
    const float* x = (const float*)d_in[0];
    float* out = (float*)d_out;
    half_t* phiA = (half_t*)d_ws;
    half_t* phiB = (half_t*)((char*)d_ws + PHI_BYTES);
    half_t* vt   = (half_t*)((char*)d_ws + 2 * PHI_BYTES);
    precompute_kernel<<<dim3(1024), 256, 0, stream>>>(x, phiA, phiB, vt);
    attn_kernel<<<dim3(1024), 256, 0, stream>>>(phiA, phiB, vt, out);
}

// Round 15
// 105.410 us; speedup vs baseline: 1.7144x; 1.7144x over previous
//
#include <hip/hip_runtime.h>

#define B_  8
#define S_  1024
#define E_  512
#define LOG2E 1.44269504088896340736f

typedef _Float16 half_t;
typedef _Float16 half2_t __attribute__((ext_vector_type(2)));
typedef _Float16 half8_t __attribute__((ext_vector_type(8)));
typedef float    floatx16 __attribute__((ext_vector_type(16)));
typedef unsigned int uint2v __attribute__((ext_vector_type(2)));
typedef unsigned int uint4v __attribute__((ext_vector_type(4)));

#define PHI_BYTES ((size_t)64 * S_ * 32 * 2)       // 4 MB per phi table
#define VT_BYTES  ((size_t)64 * 16 * 4096 * 2)     // 8 MB (tiled)

// ---------------------------------------------------------------------------
// Precompute (byte-identical to the passing r12 version): Phi tables
// (B = exact f16 features; A = H-block pre-scaled by log2e in f32 before the
// single f16 rounding) and V^T tiled [bh][chunk][slot][d][e] f16, produced
// with the same XCD bh-affinity as attn so the 2 MB/XCD table set is
// L2-resident for the consumer.
// ---------------------------------------------------------------------------
__global__ __launch_bounds__(256, 4) void precompute_kernel(const float* __restrict__ x,
                                                            half_t* __restrict__ phiA,
                                                            half_t* __restrict__ phiB,
                                                            half_t* __restrict__ vt) {
    const int orig = blockIdx.x;
    const int xcd  = orig & 7, slot = orig >> 3;
    const int bh   = xcd * 8 + (slot & 7);
    const int chunk = slot >> 3;
    const int b  = bh >> 3, h = bh & 7;
    const int j0 = chunk * 64;
    const int t  = threadIdx.x;
    __shared__ __align__(16) float vf[64][76];

    const float* xb = x + (size_t)b * S_ * E_ + h * 64;

    {
        const int j = t >> 2, dq = (t & 3) * 4;
        const float* row = xb + (size_t)(j0 + j) * E_;
        #pragma unroll
        for (int q = 0; q < 4; ++q)
            *(float4*)&vf[j][dq + q * 16] = *(const float4*)(row + dq + q * 16);
    }
    __syncthreads();

    if (t < 128) {
        const int jj = t >> 1, sel = t & 1;
        float4 xw = *(const float4*)&vf[jj][sel * 4];
        float xi[4] = {xw.x, xw.y, xw.z, xw.w};
        float c[4], s[4];
        #pragma unroll
        for (int q = 0; q < 4; ++q) {
            float v = xi[q] * 0.5f;
            c[q] = __cosf(v); s[q] = __sinf(v);
        }
        float pa[4] = {c[0]*c[1], s[0]*c[1], c[0]*s[1], s[0]*s[1]};
        float pb[4] = {c[2]*c[3], s[2]*c[3], c[2]*s[3], s[2]*s[3]};
        const float scale = sel ? LOG2E : 1.0f;
        half_t hB[16], hA[16];
        #pragma unroll
        for (int f = 0; f < 16; ++f) {
            float v = pa[f & 3] * pb[f >> 2];
            hB[f] = (half_t)v;
            hA[f] = (half_t)(v * scale);
        }
        size_t off = ((size_t)bh * S_ + j0 + jj) * 32 + (sel ? 0 : 16);
        *(half8_t*)(phiB + off)     = *(half8_t*)&hB[0];
        *(half8_t*)(phiB + off + 8) = *(half8_t*)&hB[8];
        *(half8_t*)(phiA + off)     = *(half8_t*)&hA[0];
        *(half8_t*)(phiA + off + 8) = *(half8_t*)&hA[8];
    }

    {
        const int d = t >> 2, jg = (t & 3) * 16;
        half_t hv[16];
        #pragma unroll
        for (int k = 0; k < 16; ++k) hv[k] = (half_t)vf[jg + k][d];
        const int slot0 = (t & 3) * 2;
        half_t* base = vt + ((size_t)bh * 16 + chunk) * 4096;
        *(half8_t*)(base + (slot0 + 0) * 512 + d * 8) = *(half8_t*)&hv[0];
        *(half8_t*)(base + (slot0 + 1) * 512 + d * 8) = *(half8_t*)&hv[8];
    }
}

// ---------------------------------------------------------------------------
// Main kernel, STAGING-FREE: V^T B-fragments are read DIRECTLY from the vt
// table in global memory (L2-resident by XCD affinity: 2 MB/XCD < 4 MB L2).
// Removes ALL of r12's pipeline machinery — no global_load_lds, no double
// buffer, no s_barrier in the loop, no vmcnt/sched_barrier asm. The loop
// body is pure independent loads + MFMA + VALU; compiler schedules freely.
// (Common-mistake #7: LDS-staging L2-fit data is pure overhead, m169 +26%.)
// Same bytes, same per-(i,j) math, same accumulation order as passing r12
// => bit-identical output. Grid/wave mapping identical to r12. Epilogue
// keeps plain static LDS (no union) + one __syncthreads.
// ---------------------------------------------------------------------------
__global__ __launch_bounds__(256, 2) void attn_kernel(const half_t* __restrict__ phiA,
                                                      const half_t* __restrict__ phiB,
                                                      const half_t* __restrict__ vt,
                                                      float* __restrict__ out) {
    const int orig = blockIdx.x;
    const int xcd  = orig & 7, slot = orig >> 3;
    const int bh   = xcd * 8 + (slot & 7);      // 8 bh per XCD
    const int iblk = slot >> 3;                  // 16 i-blocks
    const int b    = bh >> 3, h = bh & 7;
    const int i0   = iblk * 64;
    const int t    = threadIdx.x;
    const int wv   = t >> 6, ln = t & 63;
    const int m    = ln & 31, hf = ln >> 5;
    const int ib   = wv >> 1, jb = wv & 1;

    __shared__ float sh_red[2][32][64];   // jb=1 partial O (epilogue only)
    __shared__ float sh_den[2][64];

    const half_t* phbA = phiA + (size_t)bh * S_ * 32;
    const half_t* phbB = phiB + (size_t)bh * S_ * 32;
    const half_t* vtb  = vt + (size_t)bh * 65536;

    half8_t biH, biL;
    {
        const half_t* pr = phbB + (size_t)(i0 + ib * 32 + m) * 32 + hf * 8;
        biH = *(const half8_t*)pr;
        biL = *(const half8_t*)(pr + 16);
    }

    floatx16 acc0, acc1, z;
    #pragma unroll
    for (int k = 0; k < 16; ++k) { acc0[k] = 0.f; acc1[k] = 0.f; z[k] = 0.f; }
    float d0 = 0.f, d1 = 0.f;

    for (int tt = 0; tt < 4; ++tt) {        // 4 periods x 256 j
        const half_t* vbase = vtb + (size_t)tt * 16384;
        #pragma unroll
        for (int qi = 0; qi < 4; ++qi) {
            const int q = jb + 2 * qi;

            // B-frags direct from L2-resident vt (identical bytes to r12's
            // staged reads): lanes 0-31 / 32-63 each contiguous 512 B.
            half8_t b00 = *(const half8_t*)&vbase[(q * 4 + 0 + hf) * 512 + m * 8];
            half8_t b01 = *(const half8_t*)&vbase[(q * 4 + 2 + hf) * 512 + m * 8];
            half8_t b10 = *(const half8_t*)&vbase[(q * 4 + 0 + hf) * 512 + (32 + m) * 8];
            half8_t b11 = *(const half8_t*)&vbase[(q * 4 + 2 + hf) * 512 + (32 + m) * 8];

            // Phi_j direct (L2-resident)
            const half_t* ar = phbA + (size_t)(tt * 256 + q * 32 + m) * 32 + hf * 8;
            half8_t ajH = *(const half8_t*)ar;
            half8_t ajL = *(const half8_t*)(ar + 16);

            // S^T: lane holds j=(r&3)+8*(r>>2)+4*hf (this sub-tile), i=m
            floatx16 sH = __builtin_amdgcn_mfma_f32_32x32x16_f16(ajH, biH, z, 0, 0, 0);
            floatx16 sL = __builtin_amdgcn_mfma_f32_32x32x16_f16(ajL, biL, z, 0, 0, 0);

            // P = 2^|sH'*sL| = e^|s| (H pre-scaled by log2e), packed in regs
            unsigned int dwa[4], dwb[4];
            #pragma unroll
            for (int g = 0; g < 4; ++g) {
                float p[4];
                #pragma unroll
                for (int r = 0; r < 4; ++r) {
                    float sc = sH[4 * g + r] * sL[4 * g + r];
                    p[r] = __builtin_amdgcn_exp2f(__builtin_fabsf(sc));
                }
                d0 += p[0] + p[2];
                d1 += p[1] + p[3];
                half2_t ha = {(half_t)p[0], (half_t)p[1]};
                half2_t hb = {(half_t)p[2], (half_t)p[3]};
                dwa[g] = __builtin_bit_cast(unsigned int, ha);
                dwb[g] = __builtin_bit_cast(unsigned int, hb);
            }
            uint2v swA0 = __builtin_amdgcn_permlane32_swap(dwa[0], dwa[1], false, false);
            uint2v swB0 = __builtin_amdgcn_permlane32_swap(dwb[0], dwb[1], false, false);
            uint2v swA1 = __builtin_amdgcn_permlane32_swap(dwa[2], dwa[3], false, false);
            uint2v swB1 = __builtin_amdgcn_permlane32_swap(dwb[2], dwb[3], false, false);
            half8_t ap0 = __builtin_bit_cast(half8_t, (uint4v){swA0.x, swB0.x, swA0.y, swB0.y});
            half8_t ap1 = __builtin_bit_cast(half8_t, (uint4v){swA1.x, swB1.x, swA1.y, swB1.y});

            acc0 = __builtin_amdgcn_mfma_f32_32x32x16_f16(ap0, b00, acc0, 0, 0, 0);
            acc0 = __builtin_amdgcn_mfma_f32_32x32x16_f16(ap1, b01, acc0, 0, 0, 0);
            acc1 = __builtin_amdgcn_mfma_f32_32x32x16_f16(ap0, b10, acc1, 0, 0, 0);
            acc1 = __builtin_amdgcn_mfma_f32_32x32x16_f16(ap1, b11, acc1, 0, 0, 0);
        }
    }

    // ---- epilogue: combine hf halves of denominator, then jb partials of O
    float dtot = d0 + d1;
    dtot += __shfl_xor(dtot, 32, 64);
    sh_den[jb][ib * 32 + m] = dtot;
    if (jb == 1) {
        #pragma unroll
        for (int reg = 0; reg < 16; ++reg) {
            int il = (reg & 3) + 8 * (reg >> 2) + 4 * hf;
            sh_red[ib][il][m]      = acc0[reg];
            sh_red[ib][il][32 + m] = acc1[reg];
        }
    }
    __syncthreads();
    if (jb == 0) {
        #pragma unroll
        for (int reg = 0; reg < 16; ++reg) {
            int il = (reg & 3) + 8 * (reg >> 2) + 4 * hf;
            float inv = 1.f / (sh_den[0][ib * 32 + il] + sh_den[1][ib * 32 + il]);
            size_t base = ((size_t)(b * S_ + i0 + ib * 32 + il)) * E_ + h * 64 + m;
            __builtin_nontemporal_store((acc0[reg] + sh_red[ib][il][m])      * inv, &out[base]);
            __builtin_nontemporal_store((acc1[reg] + sh_red[ib][il][32 + m]) * inv, &out[base + 32]);
        }
    }
}

extern "C" void kernel_launch(void* const* d_in, const int* in_sizes, int n_in,
                              void* d_out, int out_size, void* d_ws, size_t ws_size,
                              hipStream_t stream) {
    const float* x = (const float*)d_in[0];
    float* out = (float*)d_out;
    half_t* phiA = (half_t*)d_ws;
    half_t* phiB = (half_t*)((char*)d_ws + PHI_BYTES);
    half_t* vt   = (half_t*)((char*)d_ws + 2 * PHI_BYTES);
    precompute_kernel<<<dim3(1024), 256, 0, stream>>>(x, phiA, phiB, vt);
    attn_kernel<<<dim3(1024), 256, 0, stream>>>(phiA, phiB, vt, out);
}

// Round 16
// 92.440 us; speedup vs baseline: 1.9550x; 1.1403x over previous
//
#include <hip/hip_runtime.h>

#define B_  8
#define S_  1024
#define E_  512
#define TI  64
#define TJ  64
#define LOG2E 1.44269504088896340736f

typedef _Float16 half_t;
typedef _Float16 half2_t __attribute__((ext_vector_type(2)));
typedef _Float16 half8_t __attribute__((ext_vector_type(8)));
typedef float    floatx16 __attribute__((ext_vector_type(16)));
typedef unsigned int uint2v __attribute__((ext_vector_type(2)));
typedef unsigned int uint4v __attribute__((ext_vector_type(4)));

#define PHI_BYTES ((size_t)64 * S_ * 32 * 2)       // 4 MB per phi table
#define VT_BYTES  ((size_t)64 * 16 * 4096 * 2)     // 8 MB (tiled)

#define GLOAD_LDS16(g, l)                                                        \
    __builtin_amdgcn_global_load_lds((const __attribute__((address_space(1))) void*)(g), \
                                     (__attribute__((address_space(3))) void*)(l), 16, 0, 0)

// ---------------------------------------------------------------------------
// Precompute: Phi tables (B = exact f16 features; A = H-block pre-scaled by
// log2e in f32 before the single f16 rounding) and V^T tiled as the exact
// per-chunk LDS image [bh][chunk][slot][d][e] f16. 1D grid 1024 with the
// same XCD bh-affinity as attn (producer/consumer L2 locality).
// ---------------------------------------------------------------------------
__global__ __launch_bounds__(256, 4) void precompute_kernel(const float* __restrict__ x,
                                                            half_t* __restrict__ phiA,
                                                            half_t* __restrict__ phiB,
                                                            half_t* __restrict__ vt) {
    const int orig = blockIdx.x;
    const int xcd  = orig & 7, slot = orig >> 3;
    const int bh   = xcd * 8 + (slot & 7);      // 8 bh per XCD (matches attn)
    const int chunk = slot >> 3;                 // 16 j-chunks
    const int b  = bh >> 3, h = bh & 7;
    const int j0 = chunk * 64;
    const int t  = threadIdx.x;
    __shared__ __align__(16) float vf[64][76];   // stride 304 B (16B-aligned)

    const float* xb = x + (size_t)b * S_ * E_ + h * 64;

    // Phase A: 64 j x 64 d floats, float4 loads
    {
        const int j = t >> 2, dq = (t & 3) * 4;
        const float* row = xb + (size_t)(j0 + j) * E_;
        #pragma unroll
        for (int q = 0; q < 4; ++q)
            *(float4*)&vf[j][dq + q * 16] = *(const float4*)(row + dq + q * 16);
    }
    __syncthreads();

    // Phase B1 (threads 0..127): Phi features (math identical to verified r1)
    if (t < 128) {
        const int jj = t >> 1, sel = t & 1;      // sel=1 -> wires 4..7 (H block)
        float4 xw = *(const float4*)&vf[jj][sel * 4];
        float xi[4] = {xw.x, xw.y, xw.z, xw.w};
        float c[4], s[4];
        #pragma unroll
        for (int q = 0; q < 4; ++q) {
            float v = xi[q] * 0.5f;
            c[q] = __cosf(v); s[q] = __sinf(v);
        }
        float pa[4] = {c[0]*c[1], s[0]*c[1], c[0]*s[1], s[0]*s[1]};
        float pb[4] = {c[2]*c[3], s[2]*c[3], c[2]*s[3], s[2]*s[3]};
        const float scale = sel ? LOG2E : 1.0f;   // scale H features in A table only
        half_t hB[16], hA[16];
        #pragma unroll
        for (int f = 0; f < 16; ++f) {
            float v = pa[f & 3] * pb[f >> 2];
            hB[f] = (half_t)v;
            hA[f] = (half_t)(v * scale);
        }
        size_t off = ((size_t)bh * S_ + j0 + jj) * 32 + (sel ? 0 : 16);
        *(half8_t*)(phiB + off)     = *(half8_t*)&hB[0];
        *(half8_t*)(phiB + off + 8) = *(half8_t*)&hB[8];
        *(half8_t*)(phiA + off)     = *(half8_t*)&hA[0];
        *(half8_t*)(phiA + off + 8) = *(half8_t*)&hA[8];
    }

    // Phase B2: V^T tiled — thread owns (d, 16 consecutive j = 2 slots)
    {
        const int d = t >> 2, jg = (t & 3) * 16;
        half_t hv[16];
        #pragma unroll
        for (int k = 0; k < 16; ++k) hv[k] = (half_t)vf[jg + k][d];
        const int slot0 = (t & 3) * 2;
        half_t* base = vt + ((size_t)bh * 16 + chunk) * 4096;
        *(half8_t*)(base + (slot0 + 0) * 512 + d * 8) = *(half8_t*)&hv[0];
        *(half8_t*)(base + (slot0 + 1) * 512 + d * 8) = *(half8_t*)&hv[8];
    }
}

// ---------------------------------------------------------------------------
// Main kernel — SESSION BEST (r7, 93.7 us measured). 1D grid 1024, XCD
// bh-affinity swizzle. 4 waves = 2 i-bands x 2 j-bands. Distance-1 V double
// buffer via lane-linear global_load_lds (staging matters: removing it cost
// +10 us, r15 — LDS reuse halves L2 traffic), wrapped Phi_j register
// prefetch, counted s_waitcnt vmcnt(2), one barrier per chunk, unroll 2.
// __launch_bounds__(256,2): 256-reg envelope, no spill (the (256,3)/(256,4)
// caps forced arch VGPR=64 and spilled ~100+ MB scratch — r3/r6/r13).
// Occupancy/barrier/prefetch knobs all measured null (r5/r6/r12).
// ---------------------------------------------------------------------------
__global__ __launch_bounds__(256, 2) void attn_kernel(const half_t* __restrict__ phiA,
                                                      const half_t* __restrict__ phiB,
                                                      const half_t* __restrict__ vt,
                                                      float* __restrict__ out) {
    const int orig = blockIdx.x;
    const int xcd  = orig & 7, slot = orig >> 3;
    const int bh   = xcd * 8 + (slot & 7);      // 8 bh per XCD
    const int iblk = slot >> 3;                  // 16 i-blocks
    const int b    = bh >> 3, h = bh & 7;
    const int i0   = iblk * TI;
    const int t    = threadIdx.x;
    const int wv   = t >> 6, ln = t & 63;
    const int m    = ln & 31, hf = ln >> 5;
    const int ib   = wv >> 1, jb = wv & 1;

    // sh_v (main loop) and sh_red (epilogue only) share storage: lifetimes are
    // disjoint, separated by a full __syncthreads() drain after the loop.
    __shared__ __align__(16) unsigned char smem_u[16384];
    half_t (&sh_v)[2][4096]     = *reinterpret_cast<half_t(*)[2][4096]>(smem_u);
    float  (&sh_red)[2][32][64] = *reinterpret_cast<float(*)[2][32][64]>(smem_u);
    __shared__ float sh_den[2][64];

    const half_t* phbA = phiA + (size_t)bh * S_ * 32;
    const half_t* phbB = phiB + (size_t)bh * S_ * 32;
    const half_t* vtb  = vt + (size_t)bh * 16 * 4096;

    half8_t biH, biL;
    {
        const half_t* pr = phbB + (size_t)(i0 + ib * 32 + m) * 32 + hf * 8;
        biH = *(const half8_t*)pr;
        biL = *(const half8_t*)(pr + 16);
    }

    floatx16 acc0, acc1, z;
    #pragma unroll
    for (int k = 0; k < 16; ++k) { acc0[k] = 0.f; acc1[k] = 0.f; z[k] = 0.f; }
    float d0 = 0.f, d1 = 0.f;

    const half_t* asrc = phbA + (size_t)(jb * 32 + m) * 32 + hf * 8;
    const int s0 = 2 * wv, s1 = 2 * wv + 1;

    // prologue: stage chunk 0 into buf0 (lane-linear, coalesced), prefetch aj(0)
    GLOAD_LDS16(vtb + s0 * 512 + ln * 8, &sh_v[0][s0 * 512]);
    GLOAD_LDS16(vtb + s1 * 512 + ln * 8, &sh_v[0][s1 * 512]);
    __builtin_amdgcn_sched_barrier(0);
    half8_t ajH = *(const half8_t*)(asrc);
    half8_t ajL = *(const half8_t*)(asrc + 16);
    asm volatile("s_waitcnt vmcnt(2)" ::: "memory");   // stages landed (aj in flight)
    __builtin_amdgcn_s_barrier();

    #pragma unroll 2
    for (int tt = 0; tt < 16; ++tt) {
        const int cur = tt & 1;
        const int ntt = (tt + 1) & 15;   // wrapped: always-valid prefetch address

        // stage next chunk into the other buffer (WAR-safe: its readers all
        // passed the previous end-of-chunk barrier)
        if (tt < 15) {
            const half_t* vs = vtb + (size_t)ntt * 4096;
            GLOAD_LDS16(vs + s0 * 512 + ln * 8, &sh_v[cur ^ 1][s0 * 512]);
            GLOAD_LDS16(vs + s1 * 512 + ln * 8, &sh_v[cur ^ 1][s1 * 512]);
        }
        __builtin_amdgcn_sched_barrier(0);   // pin: stages before aj loads

        // B-frags for current chunk (lane-linear ds_read_b128, conflict-free)
        const half_t* vb = sh_v[cur];
        const int q0 = jb * 4;
        half8_t b00 = *(const half8_t*)&vb[(q0 + 0 + hf) * 512 + m * 8];
        half8_t b01 = *(const half8_t*)&vb[(q0 + 2 + hf) * 512 + m * 8];
        half8_t b10 = *(const half8_t*)&vb[(q0 + 0 + hf) * 512 + (32 + m) * 8];
        half8_t b11 = *(const half8_t*)&vb[(q0 + 2 + hf) * 512 + (32 + m) * 8];

        // register-prefetch next chunk's Phi_j (branch-free, wrapped)
        const half_t* ar = asrc + (size_t)(ntt * TJ) * 32;
        half8_t ajHn = *(const half8_t*)ar;
        half8_t ajLn = *(const half8_t*)(ar + 16);

        // S^T: lane holds j=(r&3)+8*(r>>2)+4*hf (own band), i=m
        floatx16 sH = __builtin_amdgcn_mfma_f32_32x32x16_f16(ajH, biH, z, 0, 0, 0);
        floatx16 sL = __builtin_amdgcn_mfma_f32_32x32x16_f16(ajL, biL, z, 0, 0, 0);

        // P = 2^|sH'*sL| = e^|s| (H pre-scaled by log2e) — packed in registers
        unsigned int dwa[4], dwb[4];
        #pragma unroll
        for (int g = 0; g < 4; ++g) {
            float p[4];
            #pragma unroll
            for (int r = 0; r < 4; ++r) {
                float sc = sH[4 * g + r] * sL[4 * g + r];
                p[r] = __builtin_amdgcn_exp2f(__builtin_fabsf(sc));
            }
            d0 += p[0] + p[2];
            d1 += p[1] + p[3];
            half2_t ha = {(half_t)p[0], (half_t)p[1]};
            half2_t hb = {(half_t)p[2], (half_t)p[3]};
            dwa[g] = __builtin_bit_cast(unsigned int, ha);
            dwb[g] = __builtin_bit_cast(unsigned int, hb);
        }
        uint2v swA0 = __builtin_amdgcn_permlane32_swap(dwa[0], dwa[1], false, false);
        uint2v swB0 = __builtin_amdgcn_permlane32_swap(dwb[0], dwb[1], false, false);
        uint2v swA1 = __builtin_amdgcn_permlane32_swap(dwa[2], dwa[3], false, false);
        uint2v swB1 = __builtin_amdgcn_permlane32_swap(dwb[2], dwb[3], false, false);
        half8_t ap0 = __builtin_bit_cast(half8_t, (uint4v){swA0.x, swB0.x, swA0.y, swB0.y});
        half8_t ap1 = __builtin_bit_cast(half8_t, (uint4v){swA1.x, swB1.x, swA1.y, swB1.y});

        acc0 = __builtin_amdgcn_mfma_f32_32x32x16_f16(ap0, b00, acc0, 0, 0, 0);
        acc0 = __builtin_amdgcn_mfma_f32_32x32x16_f16(ap1, b01, acc0, 0, 0, 0);
        acc1 = __builtin_amdgcn_mfma_f32_32x32x16_f16(ap0, b10, acc1, 0, 0, 0);
        acc1 = __builtin_amdgcn_mfma_f32_32x32x16_f16(ap1, b11, acc1, 0, 0, 0);

        // counted handoff: own stages retired (aj prefetch stays in flight)
        if (tt < 15) { asm volatile("s_waitcnt vmcnt(2)" ::: "memory"); }
        __builtin_amdgcn_s_barrier();
        ajH = ajHn; ajL = ajLn;
    }

    // full drain before reusing sh_v's storage as sh_red
    __syncthreads();

    // ---- epilogue: combine hf halves of denominator, then jb partials of O
    float dtot = d0 + d1;
    dtot += __shfl_xor(dtot, 32, 64);
    sh_den[jb][ib * 32 + m] = dtot;
    if (jb == 1) {
        #pragma unroll
        for (int reg = 0; reg < 16; ++reg) {
            int il = (reg & 3) + 8 * (reg >> 2) + 4 * hf;
            sh_red[ib][il][m]      = acc0[reg];
            sh_red[ib][il][32 + m] = acc1[reg];
        }
    }
    __syncthreads();
    if (jb == 0) {
        #pragma unroll
        for (int reg = 0; reg < 16; ++reg) {
            int il = (reg & 3) + 8 * (reg >> 2) + 4 * hf;
            float inv = 1.f / (sh_den[0][ib * 32 + il] + sh_den[1][ib * 32 + il]);
            size_t base = ((size_t)(b * S_ + i0 + ib * 32 + il)) * E_ + h * 64 + m;
            __builtin_nontemporal_store((acc0[reg] + sh_red[ib][il][m])      * inv, &out[base]);
            __builtin_nontemporal_store((acc1[reg] + sh_red[ib][il][32 + m]) * inv, &out[base + 32]);
        }
    }
}

extern "C" void kernel_launch(void* const* d_in, const int* in_sizes, int n_in,
                              void* d_out, int out_size, void* d_ws, size_t ws_size,
                              hipStream_t stream) {
    const float* x = (const float*)d_in[0];
    float* out = (float*)d_out;
    half_t* phiA = (half_t*)d_ws;
    half_t* phiB = (half_t*)((char*)d_ws + PHI_BYTES);
    half_t* vt   = (half_t*)((char*)d_ws + 2 * PHI_BYTES);
    precompute_kernel<<<dim3(1024), 256, 0, stream>>>(x, phiA, phiB, vt);
    attn_kernel<<<dim3(1024), 256, 0, stream>>>(phiA, phiB, vt, out);
}

// Round 17
// 92.129 us; speedup vs baseline: 1.9616x; 1.0034x over previous
//
#include <hip/hip_runtime.h>

#define B_  8
#define S_  1024
#define E_  512
#define TI  64
#define TJ  64
#define LOG2E 1.44269504088896340736f

typedef _Float16 half_t;
typedef _Float16 half2_t __attribute__((ext_vector_type(2)));
typedef _Float16 half8_t __attribute__((ext_vector_type(8)));
typedef float    floatx16 __attribute__((ext_vector_type(16)));
typedef unsigned int uint2v __attribute__((ext_vector_type(2)));
typedef unsigned int uint4v __attribute__((ext_vector_type(4)));

#define PHI_BYTES ((size_t)64 * S_ * 32 * 2)       // 4 MB per phi table
#define VT_BYTES  ((size_t)64 * 16 * 4096 * 2)     // 8 MB (tiled)

#define GLOAD_LDS16(g, l)                                                        \
    __builtin_amdgcn_global_load_lds((const __attribute__((address_space(1))) void*)(g), \
                                     (__attribute__((address_space(3))) void*)(l), 16, 0, 0)

// ---------------------------------------------------------------------------
// Precompute (byte-identical to the passing r16 version): Phi tables
// (B = exact f16; A = H-block pre-scaled by log2e in f32) and V^T tiled
// [bh][chunk][slot][d][e] f16, XCD bh-affinity matching attn.
// ---------------------------------------------------------------------------
__global__ __launch_bounds__(256, 4) void precompute_kernel(const float* __restrict__ x,
                                                            half_t* __restrict__ phiA,
                                                            half_t* __restrict__ phiB,
                                                            half_t* __restrict__ vt) {
    const int orig = blockIdx.x;
    const int xcd  = orig & 7, slot = orig >> 3;
    const int bh   = xcd * 8 + (slot & 7);      // 8 bh per XCD (matches attn)
    const int chunk = slot >> 3;                 // 16 j-chunks
    const int b  = bh >> 3, h = bh & 7;
    const int j0 = chunk * 64;
    const int t  = threadIdx.x;
    __shared__ __align__(16) float vf[64][76];   // stride 304 B (16B-aligned)

    const float* xb = x + (size_t)b * S_ * E_ + h * 64;

    {
        const int j = t >> 2, dq = (t & 3) * 4;
        const float* row = xb + (size_t)(j0 + j) * E_;
        #pragma unroll
        for (int q = 0; q < 4; ++q)
            *(float4*)&vf[j][dq + q * 16] = *(const float4*)(row + dq + q * 16);
    }
    __syncthreads();

    if (t < 128) {
        const int jj = t >> 1, sel = t & 1;      // sel=1 -> wires 4..7 (H block)
        float4 xw = *(const float4*)&vf[jj][sel * 4];
        float xi[4] = {xw.x, xw.y, xw.z, xw.w};
        float c[4], s[4];
        #pragma unroll
        for (int q = 0; q < 4; ++q) {
            float v = xi[q] * 0.5f;
            c[q] = __cosf(v); s[q] = __sinf(v);
        }
        float pa[4] = {c[0]*c[1], s[0]*c[1], c[0]*s[1], s[0]*s[1]};
        float pb[4] = {c[2]*c[3], s[2]*c[3], c[2]*s[3], s[2]*s[3]};
        const float scale = sel ? LOG2E : 1.0f;   // scale H features in A table only
        half_t hB[16], hA[16];
        #pragma unroll
        for (int f = 0; f < 16; ++f) {
            float v = pa[f & 3] * pb[f >> 2];
            hB[f] = (half_t)v;
            hA[f] = (half_t)(v * scale);
        }
        size_t off = ((size_t)bh * S_ + j0 + jj) * 32 + (sel ? 0 : 16);
        *(half8_t*)(phiB + off)     = *(half8_t*)&hB[0];
        *(half8_t*)(phiB + off + 8) = *(half8_t*)&hB[8];
        *(half8_t*)(phiA + off)     = *(half8_t*)&hA[0];
        *(half8_t*)(phiA + off + 8) = *(half8_t*)&hA[8];
    }

    {
        const int d = t >> 2, jg = (t & 3) * 16;
        half_t hv[16];
        #pragma unroll
        for (int k = 0; k < 16; ++k) hv[k] = (half_t)vf[jg + k][d];
        const int slot0 = (t & 3) * 2;
        half_t* base = vt + ((size_t)bh * 16 + chunk) * 4096;
        *(half8_t*)(base + (slot0 + 0) * 512 + d * 8) = *(half8_t*)&hv[0];
        *(half8_t*)(base + (slot0 + 1) * 512 + d * 8) = *(half8_t*)&hv[8];
    }
}

// ---------------------------------------------------------------------------
// Main kernel = r16 (session best, 92.4 us) with ONE change under test:
// __launch_bounds__(256, 3) — a CLEAN 3-waves/SIMD occupancy test. The prior
// "occupancy null" (r5) compared spill-contaminated configs (r6 proved both
// (256,3)/(256,4) spilled ~100 MB); 2 waves/SIMD is the only spill-free point
// ever measured. To fit the ~170-reg unified budget at 3 waves, the Phi_j
// register PREFETCH IS DELETED (−16 regs): aj loads at loop top for the
// CURRENT chunk; latency hiding shifts from prefetch to 3-wave TLP — which
// is exactly the trade being measured. End-of-chunk waitcnt becomes vmcnt(0)
// (only the 2 stage-loads are outstanding; aj already drained before MFMA).
// All staging, indices, math byte-identical to r16.
// Decision by counters: spill -> WRITE_SIZE balloons -> revert; clean+null ->
// r16 is converged optimum; clean+win -> new best.
// ---------------------------------------------------------------------------
__global__ __launch_bounds__(256, 3) void attn_kernel(const half_t* __restrict__ phiA,
                                                      const half_t* __restrict__ phiB,
                                                      const half_t* __restrict__ vt,
                                                      float* __restrict__ out) {
    const int orig = blockIdx.x;
    const int xcd  = orig & 7, slot = orig >> 3;
    const int bh   = xcd * 8 + (slot & 7);      // 8 bh per XCD
    const int iblk = slot >> 3;                  // 16 i-blocks
    const int b    = bh >> 3, h = bh & 7;
    const int i0   = iblk * TI;
    const int t    = threadIdx.x;
    const int wv   = t >> 6, ln = t & 63;
    const int m    = ln & 31, hf = ln >> 5;
    const int ib   = wv >> 1, jb = wv & 1;

    // sh_v (main loop) and sh_red (epilogue only) share storage (disjoint
    // lifetimes, separated by a full __syncthreads() drain).
    __shared__ __align__(16) unsigned char smem_u[16384];
    half_t (&sh_v)[2][4096]     = *reinterpret_cast<half_t(*)[2][4096]>(smem_u);
    float  (&sh_red)[2][32][64] = *reinterpret_cast<float(*)[2][32][64]>(smem_u);
    __shared__ float sh_den[2][64];

    const half_t* phbA = phiA + (size_t)bh * S_ * 32;
    const half_t* phbB = phiB + (size_t)bh * S_ * 32;
    const half_t* vtb  = vt + (size_t)bh * 16 * 4096;

    half8_t biH, biL;
    {
        const half_t* pr = phbB + (size_t)(i0 + ib * 32 + m) * 32 + hf * 8;
        biH = *(const half8_t*)pr;
        biL = *(const half8_t*)(pr + 16);
    }

    floatx16 acc0, acc1, z;
    #pragma unroll
    for (int k = 0; k < 16; ++k) { acc0[k] = 0.f; acc1[k] = 0.f; z[k] = 0.f; }
    float d0 = 0.f, d1 = 0.f;

    const half_t* asrc = phbA + (size_t)(jb * 32 + m) * 32 + hf * 8;
    const int s0 = 2 * wv, s1 = 2 * wv + 1;

    // prologue: stage chunk 0 into buf0 (lane-linear, coalesced)
    GLOAD_LDS16(vtb + s0 * 512 + ln * 8, &sh_v[0][s0 * 512]);
    GLOAD_LDS16(vtb + s1 * 512 + ln * 8, &sh_v[0][s1 * 512]);
    asm volatile("s_waitcnt vmcnt(0)" ::: "memory");   // chunk-0 stage landed
    __builtin_amdgcn_s_barrier();

    #pragma unroll 2
    for (int tt = 0; tt < 16; ++tt) {
        const int cur = tt & 1;

        // stage next chunk into the other buffer (WAR-safe after barrier)
        if (tt < 15) {
            const half_t* vs = vtb + (size_t)(tt + 1) * 4096;
            GLOAD_LDS16(vs + s0 * 512 + ln * 8, &sh_v[cur ^ 1][s0 * 512]);
            GLOAD_LDS16(vs + s1 * 512 + ln * 8, &sh_v[cur ^ 1][s1 * 512]);
        }
        __builtin_amdgcn_sched_barrier(0);   // pin: stages issued first

        // Phi_j for CURRENT chunk (no prefetch — TLP hides the L2 hit)
        const half_t* ar = asrc + (size_t)(tt * TJ) * 32;
        half8_t ajH = *(const half8_t*)ar;
        half8_t ajL = *(const half8_t*)(ar + 16);

        // B-frags for current chunk (lane-linear ds_read_b128, conflict-free)
        const half_t* vb = sh_v[cur];
        const int q0 = jb * 4;
        half8_t b00 = *(const half8_t*)&vb[(q0 + 0 + hf) * 512 + m * 8];
        half8_t b01 = *(const half8_t*)&vb[(q0 + 2 + hf) * 512 + m * 8];
        half8_t b10 = *(const half8_t*)&vb[(q0 + 0 + hf) * 512 + (32 + m) * 8];
        half8_t b11 = *(const half8_t*)&vb[(q0 + 2 + hf) * 512 + (32 + m) * 8];

        // S^T: lane holds j=(r&3)+8*(r>>2)+4*hf (own band), i=m
        floatx16 sH = __builtin_amdgcn_mfma_f32_32x32x16_f16(ajH, biH, z, 0, 0, 0);
        floatx16 sL = __builtin_amdgcn_mfma_f32_32x32x16_f16(ajL, biL, z, 0, 0, 0);

        // P = 2^|sH'*sL| = e^|s| (H pre-scaled by log2e) — packed in registers
        unsigned int dwa[4], dwb[4];
        #pragma unroll
        for (int g = 0; g < 4; ++g) {
            float p[4];
            #pragma unroll
            for (int r = 0; r < 4; ++r) {
                float sc = sH[4 * g + r] * sL[4 * g + r];
                p[r] = __builtin_amdgcn_exp2f(__builtin_fabsf(sc));
            }
            d0 += p[0] + p[2];
            d1 += p[1] + p[3];
            half2_t ha = {(half_t)p[0], (half_t)p[1]};
            half2_t hb = {(half_t)p[2], (half_t)p[3]};
            dwa[g] = __builtin_bit_cast(unsigned int, ha);
            dwb[g] = __builtin_bit_cast(unsigned int, hb);
        }
        uint2v swA0 = __builtin_amdgcn_permlane32_swap(dwa[0], dwa[1], false, false);
        uint2v swB0 = __builtin_amdgcn_permlane32_swap(dwb[0], dwb[1], false, false);
        uint2v swA1 = __builtin_amdgcn_permlane32_swap(dwa[2], dwa[3], false, false);
        uint2v swB1 = __builtin_amdgcn_permlane32_swap(dwb[2], dwb[3], false, false);
        half8_t ap0 = __builtin_bit_cast(half8_t, (uint4v){swA0.x, swB0.x, swA0.y, swB0.y});
        half8_t ap1 = __builtin_bit_cast(half8_t, (uint4v){swA1.x, swB1.x, swA1.y, swB1.y});

        acc0 = __builtin_amdgcn_mfma_f32_32x32x16_f16(ap0, b00, acc0, 0, 0, 0);
        acc0 = __builtin_amdgcn_mfma_f32_32x32x16_f16(ap1, b01, acc0, 0, 0, 0);
        acc1 = __builtin_amdgcn_mfma_f32_32x32x16_f16(ap0, b10, acc1, 0, 0, 0);
        acc1 = __builtin_amdgcn_mfma_f32_32x32x16_f16(ap1, b11, acc1, 0, 0, 0);

        // handoff: stages for next chunk retired before its ds_reads
        if (tt < 15) { asm volatile("s_waitcnt vmcnt(0)" ::: "memory"); }
        __builtin_amdgcn_s_barrier();
    }

    // full drain before reusing sh_v's storage as sh_red
    __syncthreads();

    // ---- epilogue: combine hf halves of denominator, then jb partials of O
    float dtot = d0 + d1;
    dtot += __shfl_xor(dtot, 32, 64);
    sh_den[jb][ib * 32 + m] = dtot;
    if (jb == 1) {
        #pragma unroll
        for (int reg = 0; reg < 16; ++reg) {
            int il = (reg & 3) + 8 * (reg >> 2) + 4 * hf;
            sh_red[ib][il][m]      = acc0[reg];
            sh_red[ib][il][32 + m] = acc1[reg];
        }
    }
    __syncthreads();
    if (jb == 0) {
        #pragma unroll
        for (int reg = 0; reg < 16; ++reg) {
            int il = (reg & 3) + 8 * (reg >> 2) + 4 * hf;
            float inv = 1.f / (sh_den[0][ib * 32 + il] + sh_den[1][ib * 32 + il]);
            size_t base = ((size_t)(b * S_ + i0 + ib * 32 + il)) * E_ + h * 64 + m;
            __builtin_nontemporal_store((acc0[reg] + sh_red[ib][il][m])      * inv, &out[base]);
            __builtin_nontemporal_store((acc1[reg] + sh_red[ib][il][32 + m]) * inv, &out[base + 32]);
        }
    }
}

extern "C" void kernel_launch(void* const* d_in, const int* in_sizes, int n_in,
                              void* d_out, int out_size, void* d_ws, size_t ws_size,
                              hipStream_t stream) {
    const float* x = (const float*)d_in[0];
    float* out = (float*)d_out;
    half_t* phiA = (half_t*)d_ws;
    half_t* phiB = (half_t*)((char*)d_ws + PHI_BYTES);
    half_t* vt   = (half_t*)((char*)d_ws + 2 * PHI_BYTES);
    precompute_kernel<<<dim3(1024), 256, 0, stream>>>(x, phiA, phiB, vt);
    attn_kernel<<<dim3(1024), 256, 0, stream>>>(phiA, phiB, vt, out);
}